// Round 11
// baseline (490.093 us; speedup 1.0000x reference)
//
#include <hip/hip_runtime.h>
#include <cmath>
#include <cstdint>

#define DINL __device__ __forceinline__

namespace {

constexpr int Nn = 20000, Ee = 320000, Gg = 256, Dd = 256, Pp = 16;
constexpr int Npad = 20096;  // 157 * 128
constexpr float EPSf = 1e-7f, Rf = 0.5f, TEMPf = 0.2f;

typedef unsigned short u16;
typedef __attribute__((ext_vector_type(8))) short short8;
typedef __attribute__((ext_vector_type(4))) float floatx4;
typedef __attribute__((ext_vector_type(2))) unsigned int u2v;
typedef __attribute__((ext_vector_type(4))) unsigned int u4v;

DINL float waveSum(float x) {
#pragma unroll
  for (int off = 32; off > 0; off >>= 1) x += __shfl_xor(x, off, 64);
  return x;
}

DINL u16 f2bf(float f) {
  unsigned u = __float_as_uint(f);
  unsigned r = u + 0x7fffu + ((u >> 16) & 1u);
  return (u16)(r >> 16);
}
DINL float bf2f(u16 h) { return __uint_as_float(((unsigned)h) << 16); }

// ---------- merged setup: deg | weight split | proto-contrib | x->bf16 | goff --
__global__ void k_setup(const int* __restrict__ dst, int* __restrict__ deg,
                        const float* __restrict__ W1, const float* __restrict__ W2,
                        const float* __restrict__ Wm1, u16* __restrict__ W1th,
                        u16* __restrict__ W1tl, u16* __restrict__ W2th,
                        u16* __restrict__ W2tl, u16* __restrict__ Wm1th,
                        u16* __restrict__ Wm1tl, const float* __restrict__ proto,
                        const float* __restrict__ bm1, float* __restrict__ pcb,
                        float* __restrict__ pnorm, const float* __restrict__ x,
                        u16* __restrict__ xbf, const int* __restrict__ batch,
                        int* __restrict__ goff) {
  const int eB = (Ee + 255) / 256;
  int blk = blockIdx.x;
  int tid = threadIdx.x;
  if (blk < eB) {  // degree count
    int e = blk * 256 + tid;
    if (e < Ee) atomicAdd(&deg[dst[e]], 1);
  } else if (blk < eB + 640) {  // weight split/transpose
    int idx = (blk - eB) * 256 + tid;
    const float* W;
    u16 *th, *tl;
    int K;
    if (idx < 128 * 256) {
      W = W1; th = W1th; tl = W1tl; K = 128;
    } else if (idx < 128 * 256 + 256 * 256) {
      idx -= 128 * 256;
      W = W2; th = W2th; tl = W2tl; K = 256;
    } else {
      idx -= 128 * 256 + 256 * 256;
      W = Wm1; th = Wm1th; tl = Wm1tl; K = 256;
    }
    int k = idx >> 8, n = idx & 255;
    float v = W[idx];
    u16 h = f2bf(v);
    th[(size_t)n * K + k] = h;
    tl[(size_t)n * K + k] = f2bf(v - bf2f(h));
  } else if (blk < eB + 656) {  // proto_contrib + proto norms
    int p = blk - eB - 640;
    float s = bm1[tid];
    for (int k = 0; k < Dd; k++)
      s += proto[p * Dd + k] * Wm1[(size_t)(Dd + k) * Dd + tid];
    pcb[p * Dd + tid] = s;
    if (tid < 64) {
      float4 v = ((const float4*)(proto + (size_t)p * Dd))[tid];
      float nsq = waveSum(v.x * v.x + v.y * v.y + v.z * v.z + v.w * v.w);
      if (tid == 0) {
        float n = sqrtf(nsq);
        pnorm[p] = (n == 0.f) ? EPSf : n;
      }
    }
  } else if (blk < eB + 656 + 2500) {  // x -> bf16
    int i = (blk - eB - 656) * 256 + tid;
    if (i < Nn * 128 / 4) {
      float4 v = ((const float4*)x)[i];
      u2v o;
      o.x = (unsigned)f2bf(v.x) | ((unsigned)f2bf(v.y) << 16);
      o.y = (unsigned)f2bf(v.z) | ((unsigned)f2bf(v.w) << 16);
      __builtin_nontemporal_store(o, (u2v*)&xbf[(size_t)i * 4]);
    }
  } else {  // graph offsets from sorted batch
    for (int i = tid; i < Nn; i += 256) {
      int bi = batch[i];
      int bp = (i == 0) ? -1 : batch[i - 1];
      for (int g = bp + 1; g <= bi; ++g) goff[g] = i;
      if (i == Nn - 1)
        for (int g = bi + 1; g <= Gg; ++g) goff[g] = Nn;
    }
  }
}

__global__ __launch_bounds__(1024) void k_scan(const int* __restrict__ deg,
                                               int* __restrict__ offs) {
  __shared__ int part[1024];
  int tid = threadIdx.x;
  const int chunk = (Nn + 1023) >> 10;
  int start = tid * chunk;
  int s = 0;
  for (int k = 0; k < chunk; k++) { int i = start + k; if (i < Nn) s += deg[i]; }
  part[tid] = s;
  __syncthreads();
  for (int off = 1; off < 1024; off <<= 1) {
    int v = (tid >= off) ? part[tid - off] : 0;
    __syncthreads();
    part[tid] += v;
    __syncthreads();
  }
  int run = (tid == 0) ? 0 : part[tid - 1];
  for (int k = 0; k < chunk; k++) {
    int i = start + k;
    if (i < Nn) { offs[i] = run; run += deg[i]; }
  }
  if (start < Nn && start + chunk >= Nn) offs[Nn] = run;
}

__global__ void k_fill(const int* __restrict__ src, const int* __restrict__ dst,
                       const int* __restrict__ offs, int* __restrict__ cursor,
                       int* __restrict__ csr) {
  int e = blockIdx.x * 256 + threadIdx.x;
  if (e < Ee) {
    int d = dst[e];
    int pos = atomicAdd(&cursor[d], 1);
    csr[offs[d] + pos] = src[e];
  }
}

// ---------- 128B row-slice loader ----------
template <int DIM, int EPL, bool INBF>
DINL void slice(float r[EPL], const void* __restrict__ hv, int row, int ce) {
  if constexpr (INBF) {
    const u16* p = (const u16*)hv + (size_t)row * DIM + ce;
    ushort4 u = *(const ushort4*)p;
    r[0] = bf2f(u.x); r[1] = bf2f(u.y); r[2] = bf2f(u.z); r[3] = bf2f(u.w);
  } else {
    const float* p = (const float*)hv + (size_t)row * DIM + ce;
    float2 u = *(const float2*)p;
    r[0] = u.x; r[1] = u.y;
  }
}

// ---------- chunked edge aggregation (R6-proven form; at replication roofline) --
template <int DIM, int MODE, bool INBF, bool OSPL>
__global__ __launch_bounds__(256) void k_aggc(
    const void* __restrict__ hv, const float* __restrict__ nb,
    const int* __restrict__ offs, const int* __restrict__ csr,
    u16* __restrict__ oh, u16* __restrict__ ol) {
  constexpr int EPL = INBF ? 4 : 2;
  constexpr int COLS = EPL * 16;
  constexpr int CHUNKS = DIM / COLS;
  int c = (int)(blockIdx.x % CHUNKS);
  int grp = (int)(blockIdx.x / CHUNKS);
  int wv = threadIdx.x >> 6, lane = threadIdx.x & 63;
  int sub = lane >> 4, l = lane & 15;
  int node = grp * 16 + wv * 4 + sub;
  if (node >= Nn) return;
  int ce = c * COLS + l * EPL;
  float self[EPL], ts[EPL];
  slice<DIM, EPL, INBF>(self, hv, node, ce);
#pragma unroll
  for (int j = 0; j < EPL; j++) ts[j] = 0.f;
  int beg = offs[node], end = offs[node + 1];
  int k = beg;
  for (; k + 4 <= end; k += 4) {
    int s0 = csr[k], s1 = csr[k + 1], s2 = csr[k + 2], s3 = csr[k + 3];
    float r0[EPL], r1[EPL], r2[EPL], r3[EPL];
    slice<DIM, EPL, INBF>(r0, hv, s0, ce);
    slice<DIM, EPL, INBF>(r1, hv, s1, ce);
    slice<DIM, EPL, INBF>(r2, hv, s2, ce);
    slice<DIM, EPL, INBF>(r3, hv, s3, ce);
    if (MODE == 0) {
#pragma unroll
      for (int j = 0; j < EPL; j++) ts[j] += (r0[j] + r1[j]) + (r2[j] + r3[j]);
    } else {
      float w0 = nb[s0], w1 = nb[s1], w2 = nb[s2], w3 = nb[s3];
      if (MODE == 1) { w0 *= w0; w1 *= w1; w2 *= w2; w3 *= w3; }
#pragma unroll
      for (int j = 0; j < EPL; j++)
        ts[j] += (w0 * r0[j] + w1 * r1[j]) + (w2 * r2[j] + w3 * r3[j]);
    }
  }
  for (; k < end; k++) {
    int s = csr[k];
    float r[EPL];
    slice<DIM, EPL, INBF>(r, hv, s, ce);
    if (MODE == 0) {
#pragma unroll
      for (int j = 0; j < EPL; j++) ts[j] += r[j];
    } else {
      float wq = nb[s];
      if (MODE == 1) wq *= wq;
#pragma unroll
      for (int j = 0; j < EPL; j++) ts[j] += wq * r[j];
    }
  }
  float val[EPL];
  if (MODE == 0) {
#pragma unroll
    for (int j = 0; j < EPL; j++) val[j] = self[j] + ts[j];
  } else if (MODE == 1) {
    float wi = nb[node];
#pragma unroll
    for (int j = 0; j < EPL; j++) val[j] = wi * (self[j] + ts[j]);
  } else {
    float wi = nb[node];
#pragma unroll
    for (int j = 0; j < EPL; j++) val[j] = self[j] + wi * ts[j];
  }
  u16 hs[EPL], ls[EPL];
#pragma unroll
  for (int j = 0; j < EPL; j++) {
    hs[j] = f2bf(val[j]);
    if (OSPL) ls[j] = f2bf(val[j] - bf2f(hs[j]));
  }
  u16* po = oh + (size_t)node * DIM + ce;
  if constexpr (EPL == 2) {
    unsigned v = (unsigned)hs[0] | ((unsigned)hs[1] << 16);
    __builtin_nontemporal_store(v, (unsigned*)po);
  } else {
    u2v v;
    v.x = (unsigned)hs[0] | ((unsigned)hs[1] << 16);
    v.y = (unsigned)hs[2] | ((unsigned)hs[3] << 16);
    __builtin_nontemporal_store(v, (u2v*)po);
  }
  if constexpr (OSPL) {
    u16* pl = ol + (size_t)node * DIM + ce;
    if constexpr (EPL == 2) {
      unsigned v = (unsigned)ls[0] | ((unsigned)ls[1] << 16);
      __builtin_nontemporal_store(v, (unsigned*)pl);
    } else {
      u2v v;
      v.x = (unsigned)ls[0] | ((unsigned)ls[1] << 16);
      v.y = (unsigned)ls[2] | ((unsigned)ls[3] << 16);
      __builtin_nontemporal_store(v, (u2v*)pl);
    }
  }
}

// ---------- MFMA GEMM, 128x64 tile, XCD-swizzled 1D grid ----------
// SPLIT: 3-MFMA split-bf16 (~f32 precision). AF32: A staged from f32 source,
// hi/lo split in-register (used by masker; avoids materializing neh/nel).
// EPI: 0 = relu+bias -> f32 store; 1 = relu+bias -> bf16 store;
//      2 = masker (pc/Wm2 dot -> prob atomics); 3 = relu+bias -> atomicAdd
//      pooling into sgemb[batch[row]] (pass-2; no sensitive argmax downstream).
template <int K, bool SPLIT, bool AF32, int EPI>
__global__ __launch_bounds__(256) void k_mm(
    const void* __restrict__ Av, const u16* __restrict__ Al,
    const u16* __restrict__ Bh, const u16* __restrict__ Bl,
    const float* __restrict__ bias,
    float* __restrict__ outF, u16* __restrict__ outH,
    const float* __restrict__ pc, const int* __restrict__ batch,
    const int* __restrict__ assign, const float* __restrict__ Wm2,
    float* __restrict__ prob, float* __restrict__ sgemb) {
  // XCD swizzle: b = g*32 + c*8 + r -> panel = g*8+r, col = c
  int b = (int)blockIdx.x;
  int g = b >> 5, lane5 = b & 31;
  int panel = g * 8 + (lane5 & 7);
  int col = lane5 >> 3;
  if (panel >= 157) return;
  int rowBase = panel * 128, colBase = col * 64;

  constexpr int SK = 40;
  __shared__ u16 AsH[128 * SK];
  __shared__ u16 AsL[SPLIT ? 128 * SK : 16];
  __shared__ u16 BsH[64 * SK];
  __shared__ u16 BsL[SPLIT ? 64 * SK : 16];
  __shared__ int ap_s[128];
  int t = threadIdx.x;
  if ((EPI == 2 || EPI == 3) && t < 128) {
    int r = rowBase + t;
    int bv = (r < Nn) ? batch[r] : 0;
    ap_s[t] = (EPI == 2) ? ((r < Nn) ? assign[bv] : 0) : bv;
  }
  int lane = t & 63, wv = t >> 6;
  int quad = lane >> 4, l16 = lane & 15;
  int wm = wv * 32;
  floatx4 acc[2][4];
#pragma unroll
  for (int mt = 0; mt < 2; mt++)
#pragma unroll
    for (int nt = 0; nt < 4; nt++) acc[mt][nt] = (floatx4){0.f, 0.f, 0.f, 0.f};

  int ar = t >> 1;            // 0..127: A row in tile (16 elements per thread)
  int ak = (t & 1) * 16;
  int bn = t >> 2;            // 0..63: B col in tile (8 u16 per thread)
  int bk = (t & 3) * 8;
  const u16* bgH = Bh + (size_t)(colBase + bn) * K + bk;
  const u16* bgL = Bl + (size_t)(colBase + bn) * K + bk;

  const u16* agH;
  const u16* agL;
  const float* agF;
  if constexpr (AF32) {
    agF = (const float*)Av + (size_t)(rowBase + ar) * K + ak;
  } else {
    agH = (const u16*)Av + (size_t)(rowBase + ar) * K + ak;
    agL = Al + (size_t)(rowBase + ar) * K + ak;
  }
  bool aok = AF32 ? (rowBase + ar < Nn) : true;

  // prologue: tile 0 into regs
  u4v cA0, cA1, cA0l, cA1l, cB0, cB0l;
  float4 fA[4];
  if constexpr (AF32) {
#pragma unroll
    for (int q = 0; q < 4; q++)
      fA[q] = aok ? ((const float4*)agF)[q] : make_float4(0.f, 0.f, 0.f, 0.f);
  } else {
    cA0 = *(const u4v*)(agH);
    cA1 = *(const u4v*)(agH + 8);
    if constexpr (SPLIT) {
      cA0l = *(const u4v*)(agL);
      cA1l = *(const u4v*)(agL + 8);
    }
  }
  cB0 = *(const u4v*)(bgH);
  if constexpr (SPLIT) cB0l = *(const u4v*)(bgL);

  for (int k0 = 0; k0 < K; k0 += 32) {
    __syncthreads();
    if constexpr (AF32) {
      // split 16 floats -> hi/lo bf16 in-register, then publish to LDS
      u16 hh[16], ll[16];
#pragma unroll
      for (int q = 0; q < 4; q++) {
        const float vv[4] = {fA[q].x, fA[q].y, fA[q].z, fA[q].w};
#pragma unroll
        for (int j = 0; j < 4; j++) {
          u16 h = f2bf(vv[j]);
          hh[q * 4 + j] = h;
          ll[q * 4 + j] = f2bf(vv[j] - bf2f(h));
        }
      }
      *(u4v*)&AsH[ar * SK + ak] = *(const u4v*)&hh[0];
      *(u4v*)&AsH[ar * SK + ak + 8] = *(const u4v*)&hh[8];
      *(u4v*)&AsL[ar * SK + ak] = *(const u4v*)&ll[0];
      *(u4v*)&AsL[ar * SK + ak + 8] = *(const u4v*)&ll[8];
    } else {
      *(u4v*)&AsH[ar * SK + ak] = cA0;
      *(u4v*)&AsH[ar * SK + ak + 8] = cA1;
      if constexpr (SPLIT) {
        *(u4v*)&AsL[ar * SK + ak] = cA0l;
        *(u4v*)&AsL[ar * SK + ak + 8] = cA1l;
      }
    }
    *(u4v*)&BsH[bn * SK + bk] = cB0;
    if constexpr (SPLIT) *(u4v*)&BsL[bn * SK + bk] = cB0l;
    __syncthreads();
    if (k0 + 32 < K) {  // prefetch next K-tile; latency overlaps MFMAs below
      if constexpr (AF32) {
#pragma unroll
        for (int q = 0; q < 4; q++)
          fA[q] = aok ? ((const float4*)(agF + k0 + 32))[q]
                      : make_float4(0.f, 0.f, 0.f, 0.f);
      } else {
        cA0 = *(const u4v*)(agH + k0 + 32);
        cA1 = *(const u4v*)(agH + k0 + 40);
        if constexpr (SPLIT) {
          cA0l = *(const u4v*)(agL + k0 + 32);
          cA1l = *(const u4v*)(agL + k0 + 40);
        }
      }
      cB0 = *(const u4v*)(bgH + k0 + 32);
      if constexpr (SPLIT) cB0l = *(const u4v*)(bgL + k0 + 32);
    }
    short8 aH[2], aL[2], bH[4], bL[4];
#pragma unroll
    for (int mt = 0; mt < 2; mt++) {
      int aoff = (wm + mt * 16 + l16) * SK + quad * 8;
      aH[mt] = *(const short8*)&AsH[aoff];
      if (SPLIT) aL[mt] = *(const short8*)&AsL[aoff];
    }
#pragma unroll
    for (int nt = 0; nt < 4; nt++) {
      int boff = (nt * 16 + l16) * SK + quad * 8;
      bH[nt] = *(const short8*)&BsH[boff];
      if (SPLIT) bL[nt] = *(const short8*)&BsL[boff];
    }
#pragma unroll
    for (int mt = 0; mt < 2; mt++)
#pragma unroll
      for (int nt = 0; nt < 4; nt++) {
        acc[mt][nt] = __builtin_amdgcn_mfma_f32_16x16x32_bf16(aH[mt], bH[nt], acc[mt][nt], 0, 0, 0);
        if constexpr (SPLIT) {
          acc[mt][nt] = __builtin_amdgcn_mfma_f32_16x16x32_bf16(aH[mt], bL[nt], acc[mt][nt], 0, 0, 0);
          acc[mt][nt] = __builtin_amdgcn_mfma_f32_16x16x32_bf16(aL[mt], bH[nt], acc[mt][nt], 0, 0, 0);
        }
      }
  }

  if constexpr (EPI == 0 || EPI == 1 || EPI == 3) {
#pragma unroll
    for (int mt = 0; mt < 2; mt++)
#pragma unroll
      for (int nt = 0; nt < 4; nt++) {
        int cc = colBase + nt * 16 + l16;
        float bv = bias[cc];
#pragma unroll
        for (int r = 0; r < 4; r++) {
          int lr = wm + mt * 16 + quad * 4 + r;
          int row = rowBase + lr;
          if (row < Nn) {
            float v = fmaxf(acc[mt][nt][r] + bv, 0.f);
            if constexpr (EPI == 0) {
              outF[(size_t)row * 256 + cc] = v;
            } else if constexpr (EPI == 1) {
              outH[(size_t)row * 256 + cc] = f2bf(v);
            } else {
              atomicAdd(&sgemb[(size_t)ap_s[lr] * 256 + cc], v);
            }
          }
        }
      }
  } else {  // EPI == 2: masker
#pragma unroll
    for (int mt = 0; mt < 2; mt++) {
      float part[4] = {0.f, 0.f, 0.f, 0.f};
#pragma unroll
      for (int nt = 0; nt < 4; nt++) {
        int cc = colBase + nt * 16 + l16;
        float wmv = Wm2[cc];
#pragma unroll
        for (int r = 0; r < 4; r++) {
          int ap = ap_s[wm + mt * 16 + quad * 4 + r];
          float tv = fmaxf(acc[mt][nt][r] + pc[ap * 256 + cc], 0.f);
          part[r] += tv * wmv;
        }
      }
#pragma unroll
      for (int r = 0; r < 4; r++) {
#pragma unroll
        for (int off = 1; off < 16; off <<= 1) part[r] += __shfl_xor(part[r], off, 64);
        if (l16 == 0) {
          int row = rowBase + wm + mt * 16 + quad * 4 + r;
          if (row < Nn) atomicAdd(&prob[row], part[r]);
        }
      }
    }
  }
}

// ---------- pool (sequential order! argmax-sensitive) + prototype argmax ------
__global__ __launch_bounds__(256) void k_poolassign(
    const float* __restrict__ h, const int* __restrict__ goff,
    const float* __restrict__ proto, const float* __restrict__ pnorm,
    int* __restrict__ assign) {
  __shared__ float row[Dd];
  int g = blockIdx.x, c = threadIdx.x;
  int beg = goff[g], end = goff[g + 1];
  float s = 0.f;
  for (int n = beg; n < end; ++n)
    s += __builtin_nontemporal_load(&h[(size_t)n * Dd + c]);
  row[c] = s;
  __syncthreads();
  if (c < 64) {
    float4 v = ((const float4*)row)[c];
    float na = sqrtf(waveSum(v.x * v.x + v.y * v.y + v.z * v.z + v.w * v.w));
    if (na == 0.f) na = EPSf;
    float best = -1e30f;
    int bi = 0;
#pragma unroll
    for (int p = 0; p < Pp; p++) {
      float4 w = *(const float4*)(proto + (size_t)p * Dd + c * 4);
      float d = waveSum(v.x * w.x + v.y * w.y + v.z * w.z + v.w * w.w);
      float sim = d / (na * pnorm[p]);
      if (sim > best) { best = sim; bi = p; }
    }
    if (c == 0) assign[g] = bi;
  }
}

// ---------- sims + NCE from atomically-pooled sgemb (pass 2) ----------
__global__ __launch_bounds__(256) void k_simfin(
    const float* __restrict__ sgemb, const float* __restrict__ proto,
    const float* __restrict__ pnorm, float* __restrict__ o_sg,
    float* __restrict__ osim, float* __restrict__ snorm,
    float* __restrict__ nceAcc) {
  __shared__ float row[Dd];
  int g = blockIdx.x, c = threadIdx.x;
  float s = sgemb[(size_t)g * Dd + c];
  row[c] = s;
  o_sg[(size_t)g * Dd + c] = s;
  __syncthreads();
  if (c < 64) {
    float4 v = ((const float4*)row)[c];
    float na = sqrtf(waveSum(v.x * v.x + v.y * v.y + v.z * v.z + v.w * v.w));
    if (na == 0.f) na = EPSf;
    float sims[Pp];
#pragma unroll
    for (int p = 0; p < Pp; p++) {
      float4 w = *(const float4*)(proto + (size_t)p * Dd + c * 4);
      float d = waveSum(v.x * w.x + v.y * w.y + v.z * w.z + v.w * w.w);
      float sim = d / (na * pnorm[p]);
      sims[p] = sim;
      if (c == p) osim[g * Pp + p] = sim;
    }
    float best = sims[0];
    int bi = 0;
#pragma unroll
    for (int p = 1; p < Pp; p++) {
      if (sims[p] > best) { best = sims[p]; bi = p; }
    }
    float pos = 0.f, neg = 0.f;
#pragma unroll
    for (int p = 0; p < Pp; p++) {
      float e = expf(sims[p] / TEMPf);
      if (p == bi) pos = e; else neg += e;
    }
    if (c == 0) {
      atomicAdd(nceAcc, -logf(pos / neg));
      snorm[g] = na;
    }
  }
}

// ---------- node_bern+KL | edge_bern+KL ----------
__global__ void k_berneb(const float* __restrict__ prob, const float* __restrict__ bm2,
                         const int* __restrict__ src, const int* __restrict__ dst,
                         float* __restrict__ ob, float* __restrict__ oe,
                         float* __restrict__ accs) {
  const int nB = (Nn + 255) / 256;
  int b = blockIdx.x;
  if (b < nB) {
    int i = b * 256 + threadIdx.x;
    float val = 0.f;
    if (i < Nn) {
      float z = prob[i] + bm2[0];
      float p = 1.f / (1.f + expf(-z));
      ob[i] = p;
      const float invA = 1.f / Rf, invB = 1.f / (1.f - Rf + EPSf);
      val = p * logf(p * invA + EPSf) + (1.f - p) * logf((1.f - p) * invB + EPSf);
    }
    val = waveSum(val);
    __shared__ float wsum[4];
    int lane = threadIdx.x & 63, wvv = threadIdx.x >> 6;
    if (lane == 0) wsum[wvv] = val;
    __syncthreads();
    if (threadIdx.x == 0) atomicAdd(accs, wsum[0] + wsum[1] + wsum[2] + wsum[3]);
  } else {
    int e = (b - nB) * 256 + threadIdx.x;
    float val = 0.f;
    if (e < Ee) {
      float zs = prob[src[e]] + bm2[0];
      float zd = prob[dst[e]] + bm2[0];
      float ps = 1.f / (1.f + expf(-zs));
      float pd = 1.f / (1.f + expf(-zd));
      float v = ps * pd;
      __builtin_nontemporal_store(v, &oe[e]);
      const float invA = 1.f / (Rf * Rf), invB = 1.f / (1.f - Rf * Rf + EPSf);
      val = v * logf(v * invA + EPSf) + (1.f - v) * logf((1.f - v) * invB + EPSf);
    }
    val = waveSum(val);
    __shared__ float wsum2[4];
    int lane = threadIdx.x & 63, wvv = threadIdx.x >> 6;
    if (lane == 0) wsum2[wvv] = val;
    __syncthreads();
    if (threadIdx.x == 0) atomicAdd(accs + 1, wsum2[0] + wsum2[1] + wsum2[2] + wsum2[3]);
  }
}

// ---------- data_sim (+ final scalar outputs folded into block 0) ----------
__global__ void k_datasim(const float* __restrict__ S, const float* __restrict__ snorm,
                          float* __restrict__ out, const float* __restrict__ accs,
                          float* __restrict__ o_kl, float* __restrict__ o_nce) {
  int i = blockIdx.x, j = threadIdx.x;
  if (i == 0 && j == 0) {
    o_kl[0] = accs[0] / (float)Nn + accs[1] / (float)Ee;
    o_nce[0] = accs[2] / (float)Gg;
  }
  __shared__ float si[Dd];
  si[j] = S[(size_t)i * Dd + j];
  __syncthreads();
  const float4* rj = (const float4*)(S + (size_t)j * Dd);
  const float4* sif = (const float4*)si;
  float d = 0.f;
#pragma unroll 4
  for (int k = 0; k < Dd / 4; k++) {
    float4 a = sif[k];
    float4 b = rj[k];
    d += a.x * b.x + a.y * b.y + a.z * b.z + a.w * b.w;
  }
  out[(size_t)i * Gg + j] = d / (snorm[i] * snorm[j]);
}

}  // namespace

extern "C" void kernel_launch(void* const* d_in, const int* in_sizes, int n_in,
                              void* d_out, int out_size, void* d_ws, size_t ws_size,
                              hipStream_t stream) {
  const float* x = (const float*)d_in[0];
  const int* ei = (const int*)d_in[1];
  const int* batch = (const int*)d_in[2];
  const float* W1 = (const float*)d_in[3];
  const float* b1 = (const float*)d_in[4];
  const float* W2 = (const float*)d_in[5];
  const float* b2 = (const float*)d_in[6];
  const float* Wm1 = (const float*)d_in[7];
  const float* bm1 = (const float*)d_in[8];
  const float* Wm2 = (const float*)d_in[9];
  const float* bm2 = (const float*)d_in[10];
  const float* proto = (const float*)d_in[11];
  const int* src = ei;
  const int* dst = ei + Ee;

  float* out = (float*)d_out;
  float* o_kl = out;
  float* o_nce = out + 1;
  float* o_sim = out + 2;
  float* o_nb = o_sim + Gg * Pp;
  float* o_eb = o_nb + Nn;
  float* o_ds = o_eb + Ee;
  float* o_sg = o_ds + Gg * Gg;
  float* o_ne = o_sg + Gg * Dd;

  char* w = (char*)d_ws;
  auto take = [&](size_t bytes) -> char* {
    char* p = w;
    w += (bytes + 255) & ~(size_t)255;
    return p;
  };
  const size_t halfR = (size_t)Npad * 256 * 2;
  float* bufB = (float*)take((size_t)Npad * 256 * 4);
  char* R2 = take(2 * halfR);
  u16* A1h = (u16*)R2;
  u16* A1l = (u16*)(R2 + (size_t)Npad * 128 * 2);
  u16* A2h = (u16*)R2;
  u16* A2l = (u16*)(R2 + halfR);
  u16* h1b = (u16*)R2;            // pass2: over A2h (dead)
  u16* a2bh = (u16*)(R2 + halfR); // pass2: over A2l (dead)
  u16* a1bh = (u16*)take((size_t)Npad * 128 * 2);
  u16* xbf = (u16*)take((size_t)Nn * 128 * 2);  // own buffer (no aliasing)

  int* csr = (int*)take((size_t)Ee * 4);
  // zero-init region (contiguous -> ONE memset): deg,cursor,prob,accs,sgemb
  int* deg = (int*)take((size_t)Nn * 4);       // 80128
  int* cursor = (int*)take((size_t)Nn * 4);    // 80128
  float* prob = (float*)take(Nn * 4);          // 80128
  float* accs = (float*)take(16);              // 256
  float* sgemb = (float*)take((size_t)Gg * Dd * 4);  // 262144
  int* offs = (int*)take((size_t)(Nn + 1) * 4);
  int* goff = (int*)take((size_t)(Gg + 1) * 4);
  float* pcb = (float*)take((size_t)Pp * Dd * 4);
  float* pnorm = (float*)take(Pp * 4);
  int* assign = (int*)take(Gg * 4);
  float* snorm = (float*)take(Gg * 4);
  u16* W1th = (u16*)take((size_t)256 * 128 * 2);
  u16* W1tl = (u16*)take((size_t)256 * 128 * 2);
  u16* W2th = (u16*)take((size_t)256 * 256 * 2);
  u16* W2tl = (u16*)take((size_t)256 * 256 * 2);
  u16* Wm1th = (u16*)take((size_t)256 * 256 * 2);
  u16* Wm1tl = (u16*)take((size_t)256 * 256 * 2);

  hipMemsetAsync(deg, 0, 3 * 80128 + 256 + (size_t)Gg * Dd * 4, stream);

  const int eB = (Ee + 255) / 256;
  const int nB = (Nn + 255) / 256;
  const int gmm = 640;  // 20 super-groups x 32, XCD-swizzled

  k_setup<<<eB + 656 + 2500 + 1, 256, 0, stream>>>(
      dst, deg, W1, W2, Wm1, W1th, W1tl, W2th, W2tl, Wm1th, Wm1tl, proto, bm1,
      pcb, pnorm, x, xbf, batch, goff);
  k_scan<<<1, 1024, 0, stream>>>(deg, offs);
  k_fill<<<eB, 256, 0, stream>>>(src, dst, offs, cursor, csr);

  // ---- pass 1 (split-bf16 GEMMs, f32 chunked gathers) ----
  k_aggc<128, 0, false, true><<<1250 * 4, 256, 0, stream>>>(x, nullptr, offs, csr, A1h, A1l);
  k_mm<128, true, false, 0><<<gmm, 256, 0, stream>>>(A1h, A1l, W1th, W1tl, b1, bufB,
                                                     nullptr, nullptr, nullptr, nullptr,
                                                     nullptr, nullptr, nullptr);
  k_aggc<256, 0, false, true><<<1250 * 8, 256, 0, stream>>>(bufB, nullptr, offs, csr, A2h, A2l);
  k_mm<256, true, false, 0><<<gmm, 256, 0, stream>>>(A2h, A2l, W2th, W2tl, b2, o_ne,
                                                     nullptr, nullptr, nullptr, nullptr,
                                                     nullptr, nullptr, nullptr);
  k_poolassign<<<Gg, 256, 0, stream>>>(o_ne, goff, proto, pnorm, assign);
  // masker: A staged from o_ne (f32), split in-register; 3-MFMA precision kept
  k_mm<256, true, true, 2><<<gmm, 256, 0, stream>>>(o_ne, nullptr, Wm1th, Wm1tl,
                                                    nullptr, nullptr, nullptr, pcb,
                                                    batch, assign, Wm2, prob, nullptr);
  k_berneb<<<nB + eB, 256, 0, stream>>>(prob, bm2, src, dst, o_nb, o_eb, accs);

  // ---- pass 2 (plain bf16 GEMMs, bf16 chunked gathers) ----
  k_aggc<128, 1, true, false><<<1250 * 2, 256, 0, stream>>>(xbf, o_nb, offs, csr, a1bh, nullptr);
  k_mm<128, false, false, 1><<<gmm, 256, 0, stream>>>(a1bh, nullptr, W1th, nullptr, b1,
                                                      nullptr, h1b, nullptr, nullptr,
                                                      nullptr, nullptr, nullptr, nullptr);
  k_aggc<256, 2, true, false><<<1250 * 4, 256, 0, stream>>>(h1b, o_nb, offs, csr, a2bh, nullptr);
  // conv2 pass-2: fused atomic pooling into sgemb (zeroed in memset)
  k_mm<256, false, false, 3><<<gmm, 256, 0, stream>>>(a2bh, nullptr, W2th, nullptr, b2,
                                                      nullptr, nullptr, nullptr, batch,
                                                      nullptr, nullptr, nullptr, sgemb);
  k_simfin<<<Gg, 256, 0, stream>>>(sgemb, proto, pnorm, o_sg, o_sim, snorm, accs + 2);
  k_datasim<<<Gg, 256, 0, stream>>>(sgemb, snorm, o_ds, accs, o_kl, o_nce);
}

// Round 12
// 451.251 us; speedup vs baseline: 1.0861x; 1.0861x over previous
//
#include <hip/hip_runtime.h>
#include <cmath>
#include <cstdint>

#define DINL __device__ __forceinline__

namespace {

constexpr int Nn = 20000, Ee = 320000, Gg = 256, Dd = 256, Pp = 16;
constexpr int Npad = 20096;  // 157 * 128
constexpr float EPSf = 1e-7f, Rf = 0.5f, TEMPf = 0.2f;

typedef unsigned short u16;
typedef __attribute__((ext_vector_type(8))) short short8;
typedef __attribute__((ext_vector_type(4))) float floatx4;
typedef __attribute__((ext_vector_type(2))) unsigned int u2v;
typedef __attribute__((ext_vector_type(4))) unsigned int u4v;

DINL float waveSum(float x) {
#pragma unroll
  for (int off = 32; off > 0; off >>= 1) x += __shfl_xor(x, off, 64);
  return x;
}

DINL u16 f2bf(float f) {
  unsigned u = __float_as_uint(f);
  unsigned r = u + 0x7fffu + ((u >> 16) & 1u);
  return (u16)(r >> 16);
}
DINL float bf2f(u16 h) { return __uint_as_float(((unsigned)h) << 16); }

// ---------- merged setup: deg | weight split | proto-contrib | x->bf16 | goff --
__global__ void k_setup(const int* __restrict__ dst, int* __restrict__ deg,
                        const float* __restrict__ W1, const float* __restrict__ W2,
                        const float* __restrict__ Wm1, u16* __restrict__ W1th,
                        u16* __restrict__ W1tl, u16* __restrict__ W2th,
                        u16* __restrict__ W2tl, u16* __restrict__ Wm1th,
                        u16* __restrict__ Wm1tl, const float* __restrict__ proto,
                        const float* __restrict__ bm1, float* __restrict__ pcb,
                        float* __restrict__ pnorm, const float* __restrict__ x,
                        u16* __restrict__ xbf, const int* __restrict__ batch,
                        int* __restrict__ goff) {
  const int eB = (Ee + 255) / 256;
  int blk = blockIdx.x;
  int tid = threadIdx.x;
  if (blk < eB) {  // degree count
    int e = blk * 256 + tid;
    if (e < Ee) atomicAdd(&deg[dst[e]], 1);
  } else if (blk < eB + 640) {  // weight split/transpose
    int idx = (blk - eB) * 256 + tid;
    const float* W;
    u16 *th, *tl;
    int K;
    if (idx < 128 * 256) {
      W = W1; th = W1th; tl = W1tl; K = 128;
    } else if (idx < 128 * 256 + 256 * 256) {
      idx -= 128 * 256;
      W = W2; th = W2th; tl = W2tl; K = 256;
    } else {
      idx -= 128 * 256 + 256 * 256;
      W = Wm1; th = Wm1th; tl = Wm1tl; K = 256;
    }
    int k = idx >> 8, n = idx & 255;
    float v = W[idx];
    u16 h = f2bf(v);
    th[(size_t)n * K + k] = h;
    tl[(size_t)n * K + k] = f2bf(v - bf2f(h));
  } else if (blk < eB + 656) {  // proto_contrib + proto norms
    int p = blk - eB - 640;
    float s = bm1[tid];
    for (int k = 0; k < Dd; k++)
      s += proto[p * Dd + k] * Wm1[(size_t)(Dd + k) * Dd + tid];
    pcb[p * Dd + tid] = s;
    if (tid < 64) {
      float4 v = ((const float4*)(proto + (size_t)p * Dd))[tid];
      float nsq = waveSum(v.x * v.x + v.y * v.y + v.z * v.z + v.w * v.w);
      if (tid == 0) {
        float n = sqrtf(nsq);
        pnorm[p] = (n == 0.f) ? EPSf : n;
      }
    }
  } else if (blk < eB + 656 + 2500) {  // x -> bf16
    int i = (blk - eB - 656) * 256 + tid;
    if (i < Nn * 128 / 4) {
      float4 v = ((const float4*)x)[i];
      u2v o;
      o.x = (unsigned)f2bf(v.x) | ((unsigned)f2bf(v.y) << 16);
      o.y = (unsigned)f2bf(v.z) | ((unsigned)f2bf(v.w) << 16);
      __builtin_nontemporal_store(o, (u2v*)&xbf[(size_t)i * 4]);
    }
  } else {  // graph offsets from sorted batch
    for (int i = tid; i < Nn; i += 256) {
      int bi = batch[i];
      int bp = (i == 0) ? -1 : batch[i - 1];
      for (int g = bp + 1; g <= bi; ++g) goff[g] = i;
      if (i == Nn - 1)
        for (int g = bi + 1; g <= Gg; ++g) goff[g] = Nn;
    }
  }
}

__global__ __launch_bounds__(1024) void k_scan(const int* __restrict__ deg,
                                               int* __restrict__ offs) {
  __shared__ int part[1024];
  int tid = threadIdx.x;
  const int chunk = (Nn + 1023) >> 10;
  int start = tid * chunk;
  int s = 0;
  for (int k = 0; k < chunk; k++) { int i = start + k; if (i < Nn) s += deg[i]; }
  part[tid] = s;
  __syncthreads();
  for (int off = 1; off < 1024; off <<= 1) {
    int v = (tid >= off) ? part[tid - off] : 0;
    __syncthreads();
    part[tid] += v;
    __syncthreads();
  }
  int run = (tid == 0) ? 0 : part[tid - 1];
  for (int k = 0; k < chunk; k++) {
    int i = start + k;
    if (i < Nn) { offs[i] = run; run += deg[i]; }
  }
  if (start < Nn && start + chunk >= Nn) offs[Nn] = run;
}

__global__ void k_fill(const int* __restrict__ src, const int* __restrict__ dst,
                       const int* __restrict__ offs, int* __restrict__ cursor,
                       int* __restrict__ csr) {
  int e = blockIdx.x * 256 + threadIdx.x;
  if (e < Ee) {
    int d = dst[e];
    int pos = atomicAdd(&cursor[d], 1);
    csr[offs[d] + pos] = src[e];
  }
}

// ---------- 128B row-slice loader ----------
template <int DIM, int EPL, bool INBF>
DINL void slice(float r[EPL], const void* __restrict__ hv, int row, int ce) {
  if constexpr (INBF) {
    const u16* p = (const u16*)hv + (size_t)row * DIM + ce;
    ushort4 u = *(const ushort4*)p;
    r[0] = bf2f(u.x); r[1] = bf2f(u.y); r[2] = bf2f(u.z); r[3] = bf2f(u.w);
  } else {
    const float* p = (const float*)hv + (size_t)row * DIM + ce;
    float2 u = *(const float2*)p;
    r[0] = u.x; r[1] = u.y;
  }
}

// ---------- chunked edge aggregation (R6-proven form; at replication roofline) --
template <int DIM, int MODE, bool INBF, bool OSPL>
__global__ __launch_bounds__(256) void k_aggc(
    const void* __restrict__ hv, const float* __restrict__ nb,
    const int* __restrict__ offs, const int* __restrict__ csr,
    u16* __restrict__ oh, u16* __restrict__ ol) {
  constexpr int EPL = INBF ? 4 : 2;
  constexpr int COLS = EPL * 16;
  constexpr int CHUNKS = DIM / COLS;
  int c = (int)(blockIdx.x % CHUNKS);
  int grp = (int)(blockIdx.x / CHUNKS);
  int wv = threadIdx.x >> 6, lane = threadIdx.x & 63;
  int sub = lane >> 4, l = lane & 15;
  int node = grp * 16 + wv * 4 + sub;
  if (node >= Nn) return;
  int ce = c * COLS + l * EPL;
  float self[EPL], ts[EPL];
  slice<DIM, EPL, INBF>(self, hv, node, ce);
#pragma unroll
  for (int j = 0; j < EPL; j++) ts[j] = 0.f;
  int beg = offs[node], end = offs[node + 1];
  int k = beg;
  for (; k + 4 <= end; k += 4) {
    int s0 = csr[k], s1 = csr[k + 1], s2 = csr[k + 2], s3 = csr[k + 3];
    float r0[EPL], r1[EPL], r2[EPL], r3[EPL];
    slice<DIM, EPL, INBF>(r0, hv, s0, ce);
    slice<DIM, EPL, INBF>(r1, hv, s1, ce);
    slice<DIM, EPL, INBF>(r2, hv, s2, ce);
    slice<DIM, EPL, INBF>(r3, hv, s3, ce);
    if (MODE == 0) {
#pragma unroll
      for (int j = 0; j < EPL; j++) ts[j] += (r0[j] + r1[j]) + (r2[j] + r3[j]);
    } else {
      float w0 = nb[s0], w1 = nb[s1], w2 = nb[s2], w3 = nb[s3];
      if (MODE == 1) { w0 *= w0; w1 *= w1; w2 *= w2; w3 *= w3; }
#pragma unroll
      for (int j = 0; j < EPL; j++)
        ts[j] += (w0 * r0[j] + w1 * r1[j]) + (w2 * r2[j] + w3 * r3[j]);
    }
  }
  for (; k < end; k++) {
    int s = csr[k];
    float r[EPL];
    slice<DIM, EPL, INBF>(r, hv, s, ce);
    if (MODE == 0) {
#pragma unroll
      for (int j = 0; j < EPL; j++) ts[j] += r[j];
    } else {
      float wq = nb[s];
      if (MODE == 1) wq *= wq;
#pragma unroll
      for (int j = 0; j < EPL; j++) ts[j] += wq * r[j];
    }
  }
  float val[EPL];
  if (MODE == 0) {
#pragma unroll
    for (int j = 0; j < EPL; j++) val[j] = self[j] + ts[j];
  } else if (MODE == 1) {
    float wi = nb[node];
#pragma unroll
    for (int j = 0; j < EPL; j++) val[j] = wi * (self[j] + ts[j]);
  } else {
    float wi = nb[node];
#pragma unroll
    for (int j = 0; j < EPL; j++) val[j] = self[j] + wi * ts[j];
  }
  u16 hs[EPL], ls[EPL];
#pragma unroll
  for (int j = 0; j < EPL; j++) {
    hs[j] = f2bf(val[j]);
    if (OSPL) ls[j] = f2bf(val[j] - bf2f(hs[j]));
  }
  u16* po = oh + (size_t)node * DIM + ce;
  if constexpr (EPL == 2) {
    unsigned v = (unsigned)hs[0] | ((unsigned)hs[1] << 16);
    __builtin_nontemporal_store(v, (unsigned*)po);
  } else {
    u2v v;
    v.x = (unsigned)hs[0] | ((unsigned)hs[1] << 16);
    v.y = (unsigned)hs[2] | ((unsigned)hs[3] << 16);
    __builtin_nontemporal_store(v, (u2v*)po);
  }
  if constexpr (OSPL) {
    u16* pl = ol + (size_t)node * DIM + ce;
    if constexpr (EPL == 2) {
      unsigned v = (unsigned)ls[0] | ((unsigned)ls[1] << 16);
      __builtin_nontemporal_store(v, (unsigned*)pl);
    } else {
      u2v v;
      v.x = (unsigned)ls[0] | ((unsigned)ls[1] << 16);
      v.y = (unsigned)ls[2] | ((unsigned)ls[3] << 16);
      __builtin_nontemporal_store(v, (u2v*)pl);
    }
  }
}

// ---------- MFMA GEMM, 128x64 tile, XCD-swizzled 1D grid ----------
// SPLIT: 3-MFMA split-bf16 (~f32 precision). AF32: A staged from f32 source,
// hi/lo split in-register (masker path; avoids materializing neh/nel).
// EPI: 0 = relu+bias -> f32 store; 1 = relu+bias -> bf16 store;
//      2 = masker (pc/Wm2 dot -> per-row prob atomics).
// NOTE (R11 lesson): do NOT fuse pooling via atomicAdd into a 256KB region —
// 5.1M cross-XCD device-scope atomics serialize at the coherence point (69us).
template <int K, bool SPLIT, bool AF32, int EPI>
__global__ __launch_bounds__(256) void k_mm(
    const void* __restrict__ Av, const u16* __restrict__ Al,
    const u16* __restrict__ Bh, const u16* __restrict__ Bl,
    const float* __restrict__ bias,
    float* __restrict__ outF, u16* __restrict__ outH,
    const float* __restrict__ pc, const int* __restrict__ batch,
    const int* __restrict__ assign, const float* __restrict__ Wm2,
    float* __restrict__ prob) {
  // XCD swizzle: b = g*32 + c*8 + r -> panel = g*8+r, col = c
  int b = (int)blockIdx.x;
  int g = b >> 5, lane5 = b & 31;
  int panel = g * 8 + (lane5 & 7);
  int col = lane5 >> 3;
  if (panel >= 157) return;
  int rowBase = panel * 128, colBase = col * 64;

  constexpr int SK = 40;
  __shared__ u16 AsH[128 * SK];
  __shared__ u16 AsL[SPLIT ? 128 * SK : 16];
  __shared__ u16 BsH[64 * SK];
  __shared__ u16 BsL[SPLIT ? 64 * SK : 16];
  __shared__ int ap_s[128];
  int t = threadIdx.x;
  if (EPI == 2 && t < 128) {
    int r = rowBase + t;
    ap_s[t] = (r < Nn) ? assign[batch[r]] : 0;
  }
  int lane = t & 63, wv = t >> 6;
  int quad = lane >> 4, l16 = lane & 15;
  int wm = wv * 32;
  floatx4 acc[2][4];
#pragma unroll
  for (int mt = 0; mt < 2; mt++)
#pragma unroll
    for (int nt = 0; nt < 4; nt++) acc[mt][nt] = (floatx4){0.f, 0.f, 0.f, 0.f};

  int ar = t >> 1;            // 0..127: A row in tile (16 elements per thread)
  int ak = (t & 1) * 16;
  int bn = t >> 2;            // 0..63: B col in tile (8 u16 per thread)
  int bk = (t & 3) * 8;
  const u16* bgH = Bh + (size_t)(colBase + bn) * K + bk;
  const u16* bgL = Bl + (size_t)(colBase + bn) * K + bk;

  const u16* agH;
  const u16* agL;
  const float* agF;
  if constexpr (AF32) {
    agF = (const float*)Av + (size_t)(rowBase + ar) * K + ak;
  } else {
    agH = (const u16*)Av + (size_t)(rowBase + ar) * K + ak;
    agL = Al + (size_t)(rowBase + ar) * K + ak;
  }
  bool aok = AF32 ? (rowBase + ar < Nn) : true;

  // prologue: tile 0 into regs
  u4v cA0, cA1, cA0l, cA1l, cB0, cB0l;
  float4 fA[4];
  if constexpr (AF32) {
#pragma unroll
    for (int q = 0; q < 4; q++)
      fA[q] = aok ? ((const float4*)agF)[q] : make_float4(0.f, 0.f, 0.f, 0.f);
  } else {
    cA0 = *(const u4v*)(agH);
    cA1 = *(const u4v*)(agH + 8);
    if constexpr (SPLIT) {
      cA0l = *(const u4v*)(agL);
      cA1l = *(const u4v*)(agL + 8);
    }
  }
  cB0 = *(const u4v*)(bgH);
  if constexpr (SPLIT) cB0l = *(const u4v*)(bgL);

  for (int k0 = 0; k0 < K; k0 += 32) {
    __syncthreads();
    if constexpr (AF32) {
      u16 hh[16], ll[16];
#pragma unroll
      for (int q = 0; q < 4; q++) {
        const float vv[4] = {fA[q].x, fA[q].y, fA[q].z, fA[q].w};
#pragma unroll
        for (int j = 0; j < 4; j++) {
          u16 h = f2bf(vv[j]);
          hh[q * 4 + j] = h;
          ll[q * 4 + j] = f2bf(vv[j] - bf2f(h));
        }
      }
      *(u4v*)&AsH[ar * SK + ak] = *(const u4v*)&hh[0];
      *(u4v*)&AsH[ar * SK + ak + 8] = *(const u4v*)&hh[8];
      *(u4v*)&AsL[ar * SK + ak] = *(const u4v*)&ll[0];
      *(u4v*)&AsL[ar * SK + ak + 8] = *(const u4v*)&ll[8];
    } else {
      *(u4v*)&AsH[ar * SK + ak] = cA0;
      *(u4v*)&AsH[ar * SK + ak + 8] = cA1;
      if constexpr (SPLIT) {
        *(u4v*)&AsL[ar * SK + ak] = cA0l;
        *(u4v*)&AsL[ar * SK + ak + 8] = cA1l;
      }
    }
    *(u4v*)&BsH[bn * SK + bk] = cB0;
    if constexpr (SPLIT) *(u4v*)&BsL[bn * SK + bk] = cB0l;
    __syncthreads();
    if (k0 + 32 < K) {  // prefetch next K-tile; latency overlaps MFMAs below
      if constexpr (AF32) {
#pragma unroll
        for (int q = 0; q < 4; q++)
          fA[q] = aok ? ((const float4*)(agF + k0 + 32))[q]
                      : make_float4(0.f, 0.f, 0.f, 0.f);
      } else {
        cA0 = *(const u4v*)(agH + k0 + 32);
        cA1 = *(const u4v*)(agH + k0 + 40);
        if constexpr (SPLIT) {
          cA0l = *(const u4v*)(agL + k0 + 32);
          cA1l = *(const u4v*)(agL + k0 + 40);
        }
      }
      cB0 = *(const u4v*)(bgH + k0 + 32);
      if constexpr (SPLIT) cB0l = *(const u4v*)(bgL + k0 + 32);
    }
    short8 aH[2], aL[2], bH[4], bL[4];
#pragma unroll
    for (int mt = 0; mt < 2; mt++) {
      int aoff = (wm + mt * 16 + l16) * SK + quad * 8;
      aH[mt] = *(const short8*)&AsH[aoff];
      if (SPLIT) aL[mt] = *(const short8*)&AsL[aoff];
    }
#pragma unroll
    for (int nt = 0; nt < 4; nt++) {
      int boff = (nt * 16 + l16) * SK + quad * 8;
      bH[nt] = *(const short8*)&BsH[boff];
      if (SPLIT) bL[nt] = *(const short8*)&BsL[boff];
    }
#pragma unroll
    for (int mt = 0; mt < 2; mt++)
#pragma unroll
      for (int nt = 0; nt < 4; nt++) {
        acc[mt][nt] = __builtin_amdgcn_mfma_f32_16x16x32_bf16(aH[mt], bH[nt], acc[mt][nt], 0, 0, 0);
        if constexpr (SPLIT) {
          acc[mt][nt] = __builtin_amdgcn_mfma_f32_16x16x32_bf16(aH[mt], bL[nt], acc[mt][nt], 0, 0, 0);
          acc[mt][nt] = __builtin_amdgcn_mfma_f32_16x16x32_bf16(aL[mt], bH[nt], acc[mt][nt], 0, 0, 0);
        }
      }
  }

  if constexpr (EPI == 0 || EPI == 1) {
#pragma unroll
    for (int mt = 0; mt < 2; mt++)
#pragma unroll
      for (int nt = 0; nt < 4; nt++) {
        int cc = colBase + nt * 16 + l16;
        float bv = bias[cc];
#pragma unroll
        for (int r = 0; r < 4; r++) {
          int row = rowBase + wm + mt * 16 + quad * 4 + r;
          if (row < Nn) {
            float v = fmaxf(acc[mt][nt][r] + bv, 0.f);
            if constexpr (EPI == 0) {
              outF[(size_t)row * 256 + cc] = v;
            } else {
              outH[(size_t)row * 256 + cc] = f2bf(v);
            }
          }
        }
      }
  } else {  // EPI == 2: masker
#pragma unroll
    for (int mt = 0; mt < 2; mt++) {
      float part[4] = {0.f, 0.f, 0.f, 0.f};
#pragma unroll
      for (int nt = 0; nt < 4; nt++) {
        int cc = colBase + nt * 16 + l16;
        float wmv = Wm2[cc];
#pragma unroll
        for (int r = 0; r < 4; r++) {
          int ap = ap_s[wm + mt * 16 + quad * 4 + r];
          float tv = fmaxf(acc[mt][nt][r] + pc[ap * 256 + cc], 0.f);
          part[r] += tv * wmv;
        }
      }
#pragma unroll
      for (int r = 0; r < 4; r++) {
#pragma unroll
        for (int off = 1; off < 16; off <<= 1) part[r] += __shfl_xor(part[r], off, 64);
        if (l16 == 0) {
          int row = rowBase + wm + mt * 16 + quad * 4 + r;
          if (row < Nn) atomicAdd(&prob[row], part[r]);
        }
      }
    }
  }
}

// ---------- pool (sequential order! argmax-sensitive) + prototype argmax ------
__global__ __launch_bounds__(256) void k_poolassign(
    const float* __restrict__ h, const int* __restrict__ goff,
    const float* __restrict__ proto, const float* __restrict__ pnorm,
    int* __restrict__ assign) {
  __shared__ float row[Dd];
  int g = blockIdx.x, c = threadIdx.x;
  int beg = goff[g], end = goff[g + 1];
  float s = 0.f;
  for (int n = beg; n < end; ++n)
    s += __builtin_nontemporal_load(&h[(size_t)n * Dd + c]);
  row[c] = s;
  __syncthreads();
  if (c < 64) {
    float4 v = ((const float4*)row)[c];
    float na = sqrtf(waveSum(v.x * v.x + v.y * v.y + v.z * v.z + v.w * v.w));
    if (na == 0.f) na = EPSf;
    float best = -1e30f;
    int bi = 0;
#pragma unroll
    for (int p = 0; p < Pp; p++) {
      float4 w = *(const float4*)(proto + (size_t)p * Dd + c * 4);
      float d = waveSum(v.x * w.x + v.y * w.y + v.z * w.z + v.w * w.w);
      float sim = d / (na * pnorm[p]);
      if (sim > best) { best = sim; bi = p; }
    }
    if (c == 0) assign[g] = bi;
  }
}

// ---------- pool + similarity + NCE (pass 2), fused ----------
__global__ __launch_bounds__(256) void k_poolsim(
    const float* __restrict__ h, const int* __restrict__ goff,
    const float* __restrict__ proto, const float* __restrict__ pnorm,
    float* __restrict__ o_sg, float* __restrict__ sgemb,
    float* __restrict__ osim, float* __restrict__ snorm,
    float* __restrict__ nceAcc) {
  __shared__ float row[Dd];
  int g = blockIdx.x, c = threadIdx.x;
  int beg = goff[g], end = goff[g + 1];
  float s = 0.f;
  for (int n = beg; n < end; ++n)
    s += __builtin_nontemporal_load(&h[(size_t)n * Dd + c]);
  row[c] = s;
  o_sg[(size_t)g * Dd + c] = s;
  sgemb[(size_t)g * Dd + c] = s;
  __syncthreads();
  if (c < 64) {
    float4 v = ((const float4*)row)[c];
    float na = sqrtf(waveSum(v.x * v.x + v.y * v.y + v.z * v.z + v.w * v.w));
    if (na == 0.f) na = EPSf;
    float sims[Pp];
#pragma unroll
    for (int p = 0; p < Pp; p++) {
      float4 w = *(const float4*)(proto + (size_t)p * Dd + c * 4);
      float d = waveSum(v.x * w.x + v.y * w.y + v.z * w.z + v.w * w.w);
      float sim = d / (na * pnorm[p]);
      sims[p] = sim;
      if (c == p) osim[g * Pp + p] = sim;
    }
    float best = sims[0];
    int bi = 0;
#pragma unroll
    for (int p = 1; p < Pp; p++) {
      if (sims[p] > best) { best = sims[p]; bi = p; }
    }
    float pos = 0.f, neg = 0.f;
#pragma unroll
    for (int p = 0; p < Pp; p++) {
      float e = expf(sims[p] / TEMPf);
      if (p == bi) pos = e; else neg += e;
    }
    if (c == 0) {
      atomicAdd(nceAcc, -logf(pos / neg));
      snorm[g] = na;
    }
  }
}

// ---------- node_bern+KL | edge_bern+KL ----------
__global__ void k_berneb(const float* __restrict__ prob, const float* __restrict__ bm2,
                         const int* __restrict__ src, const int* __restrict__ dst,
                         float* __restrict__ ob, float* __restrict__ oe,
                         float* __restrict__ accs) {
  const int nB = (Nn + 255) / 256;
  int b = blockIdx.x;
  if (b < nB) {
    int i = b * 256 + threadIdx.x;
    float val = 0.f;
    if (i < Nn) {
      float z = prob[i] + bm2[0];
      float p = 1.f / (1.f + expf(-z));
      ob[i] = p;
      const float invA = 1.f / Rf, invB = 1.f / (1.f - Rf + EPSf);
      val = p * logf(p * invA + EPSf) + (1.f - p) * logf((1.f - p) * invB + EPSf);
    }
    val = waveSum(val);
    __shared__ float wsum[4];
    int lane = threadIdx.x & 63, wvv = threadIdx.x >> 6;
    if (lane == 0) wsum[wvv] = val;
    __syncthreads();
    if (threadIdx.x == 0) atomicAdd(accs, wsum[0] + wsum[1] + wsum[2] + wsum[3]);
  } else {
    int e = (b - nB) * 256 + threadIdx.x;
    float val = 0.f;
    if (e < Ee) {
      float zs = prob[src[e]] + bm2[0];
      float zd = prob[dst[e]] + bm2[0];
      float ps = 1.f / (1.f + expf(-zs));
      float pd = 1.f / (1.f + expf(-zd));
      float v = ps * pd;
      __builtin_nontemporal_store(v, &oe[e]);
      const float invA = 1.f / (Rf * Rf), invB = 1.f / (1.f - Rf * Rf + EPSf);
      val = v * logf(v * invA + EPSf) + (1.f - v) * logf((1.f - v) * invB + EPSf);
    }
    val = waveSum(val);
    __shared__ float wsum2[4];
    int lane = threadIdx.x & 63, wvv = threadIdx.x >> 6;
    if (lane == 0) wsum2[wvv] = val;
    __syncthreads();
    if (threadIdx.x == 0) atomicAdd(accs + 1, wsum2[0] + wsum2[1] + wsum2[2] + wsum2[3]);
  }
}

// ---------- data_sim (+ final scalar outputs folded into block 0) ----------
__global__ void k_datasim(const float* __restrict__ S, const float* __restrict__ snorm,
                          float* __restrict__ out, const float* __restrict__ accs,
                          float* __restrict__ o_kl, float* __restrict__ o_nce) {
  int i = blockIdx.x, j = threadIdx.x;
  if (i == 0 && j == 0) {
    o_kl[0] = accs[0] / (float)Nn + accs[1] / (float)Ee;
    o_nce[0] = accs[2] / (float)Gg;
  }
  __shared__ float si[Dd];
  si[j] = S[(size_t)i * Dd + j];
  __syncthreads();
  const float4* rj = (const float4*)(S + (size_t)j * Dd);
  const float4* sif = (const float4*)si;
  float d = 0.f;
#pragma unroll 4
  for (int k = 0; k < Dd / 4; k++) {
    float4 a = sif[k];
    float4 b = rj[k];
    d += a.x * b.x + a.y * b.y + a.z * b.z + a.w * b.w;
  }
  out[(size_t)i * Gg + j] = d / (snorm[i] * snorm[j]);
}

}  // namespace

extern "C" void kernel_launch(void* const* d_in, const int* in_sizes, int n_in,
                              void* d_out, int out_size, void* d_ws, size_t ws_size,
                              hipStream_t stream) {
  const float* x = (const float*)d_in[0];
  const int* ei = (const int*)d_in[1];
  const int* batch = (const int*)d_in[2];
  const float* W1 = (const float*)d_in[3];
  const float* b1 = (const float*)d_in[4];
  const float* W2 = (const float*)d_in[5];
  const float* b2 = (const float*)d_in[6];
  const float* Wm1 = (const float*)d_in[7];
  const float* bm1 = (const float*)d_in[8];
  const float* Wm2 = (const float*)d_in[9];
  const float* bm2 = (const float*)d_in[10];
  const float* proto = (const float*)d_in[11];
  const int* src = ei;
  const int* dst = ei + Ee;

  float* out = (float*)d_out;
  float* o_kl = out;
  float* o_nce = out + 1;
  float* o_sim = out + 2;
  float* o_nb = o_sim + Gg * Pp;
  float* o_eb = o_nb + Nn;
  float* o_ds = o_eb + Ee;
  float* o_sg = o_ds + Gg * Gg;
  float* o_ne = o_sg + Gg * Dd;

  char* w = (char*)d_ws;
  auto take = [&](size_t bytes) -> char* {
    char* p = w;
    w += (bytes + 255) & ~(size_t)255;
    return p;
  };
  const size_t halfR = (size_t)Npad * 256 * 2;
  float* bufB = (float*)take((size_t)Npad * 256 * 4);
  char* R2 = take(2 * halfR);
  u16* A1h = (u16*)R2;
  u16* A1l = (u16*)(R2 + (size_t)Npad * 128 * 2);
  u16* A2h = (u16*)R2;
  u16* A2l = (u16*)(R2 + halfR);
  u16* h1b = (u16*)R2;            // pass2: over A2h (dead)
  u16* a2bh = (u16*)(R2 + halfR); // pass2: over A2l (dead)
  u16* a1bh = (u16*)take((size_t)Npad * 128 * 2);
  u16* xbf = (u16*)take((size_t)Nn * 128 * 2);  // own buffer (no aliasing)

  int* csr = (int*)take((size_t)Ee * 4);
  // zero-init region (contiguous -> ONE memset): deg, cursor, prob, accs
  int* deg = (int*)take((size_t)Nn * 4);       // 80128
  int* cursor = (int*)take((size_t)Nn * 4);    // 80128
  float* prob = (float*)take(Nn * 4);          // 80128
  float* accs = (float*)take(16);              // 256
  float* sgemb = (float*)take((size_t)Gg * Dd * 4);
  int* offs = (int*)take((size_t)(Nn + 1) * 4);
  int* goff = (int*)take((size_t)(Gg + 1) * 4);
  float* pcb = (float*)take((size_t)Pp * Dd * 4);
  float* pnorm = (float*)take(Pp * 4);
  int* assign = (int*)take(Gg * 4);
  float* snorm = (float*)take(Gg * 4);
  u16* W1th = (u16*)take((size_t)256 * 128 * 2);
  u16* W1tl = (u16*)take((size_t)256 * 128 * 2);
  u16* W2th = (u16*)take((size_t)256 * 256 * 2);
  u16* W2tl = (u16*)take((size_t)256 * 256 * 2);
  u16* Wm1th = (u16*)take((size_t)256 * 256 * 2);
  u16* Wm1tl = (u16*)take((size_t)256 * 256 * 2);

  hipMemsetAsync(deg, 0, 3 * 80128 + 256, stream);

  const int eB = (Ee + 255) / 256;
  const int nB = (Nn + 255) / 256;
  const int gmm = 640;  // 20 super-groups x 32, XCD-swizzled

  k_setup<<<eB + 656 + 2500 + 1, 256, 0, stream>>>(
      dst, deg, W1, W2, Wm1, W1th, W1tl, W2th, W2tl, Wm1th, Wm1tl, proto, bm1,
      pcb, pnorm, x, xbf, batch, goff);
  k_scan<<<1, 1024, 0, stream>>>(deg, offs);
  k_fill<<<eB, 256, 0, stream>>>(src, dst, offs, cursor, csr);

  // ---- pass 1 (split-bf16 GEMMs, f32 chunked gathers) ----
  k_aggc<128, 0, false, true><<<1250 * 4, 256, 0, stream>>>(x, nullptr, offs, csr, A1h, A1l);
  k_mm<128, true, false, 0><<<gmm, 256, 0, stream>>>(A1h, A1l, W1th, W1tl, b1, bufB,
                                                     nullptr, nullptr, nullptr, nullptr,
                                                     nullptr, nullptr);
  k_aggc<256, 0, false, true><<<1250 * 8, 256, 0, stream>>>(bufB, nullptr, offs, csr, A2h, A2l);
  k_mm<256, true, false, 0><<<gmm, 256, 0, stream>>>(A2h, A2l, W2th, W2tl, b2, o_ne,
                                                     nullptr, nullptr, nullptr, nullptr,
                                                     nullptr, nullptr);
  k_poolassign<<<Gg, 256, 0, stream>>>(o_ne, goff, proto, pnorm, assign);
  // masker: A staged from o_ne (f32), split in-register; 3-MFMA precision kept
  k_mm<256, true, true, 2><<<gmm, 256, 0, stream>>>(o_ne, nullptr, Wm1th, Wm1tl,
                                                    nullptr, nullptr, nullptr, pcb,
                                                    batch, assign, Wm2, prob);
  k_berneb<<<nB + eB, 256, 0, stream>>>(prob, bm2, src, dst, o_nb, o_eb, accs);

  // ---- pass 2 (plain bf16 GEMMs, bf16 chunked gathers) ----
  k_aggc<128, 1, true, false><<<1250 * 2, 256, 0, stream>>>(xbf, o_nb, offs, csr, a1bh, nullptr);
  k_mm<128, false, false, 1><<<gmm, 256, 0, stream>>>(a1bh, nullptr, W1th, nullptr, b1,
                                                      nullptr, h1b, nullptr, nullptr,
                                                      nullptr, nullptr, nullptr);
  k_aggc<256, 2, true, false><<<1250 * 4, 256, 0, stream>>>(h1b, o_nb, offs, csr, a2bh, nullptr);
  k_mm<256, false, false, 0><<<gmm, 256, 0, stream>>>(a2bh, nullptr, W2th, nullptr, b2,
                                                      bufB, nullptr, nullptr, nullptr,
                                                      nullptr, nullptr, nullptr);
  k_poolsim<<<Gg, 256, 0, stream>>>(bufB, goff, proto, pnorm, o_sg, sgemb, o_sim, snorm,
                                    accs + 2);
  k_datasim<<<Gg, 256, 0, stream>>>(sgemb, snorm, o_ds, accs, o_kl, o_nce);
}

// Round 13
// 435.264 us; speedup vs baseline: 1.1260x; 1.0367x over previous
//
#include <hip/hip_runtime.h>
#include <cmath>
#include <cstdint>

#define DINL __device__ __forceinline__

namespace {

constexpr int Nn = 20000, Ee = 320000, Gg = 256, Dd = 256, Pp = 16;
constexpr int Npad = 20096;  // 157 * 128
constexpr float EPSf = 1e-7f, Rf = 0.5f, TEMPf = 0.2f;

typedef unsigned short u16;
typedef __attribute__((ext_vector_type(8))) short short8;
typedef __attribute__((ext_vector_type(4))) float floatx4;
typedef __attribute__((ext_vector_type(2))) unsigned int u2v;
typedef __attribute__((ext_vector_type(4))) unsigned int u4v;

DINL float waveSum(float x) {
#pragma unroll
  for (int off = 32; off > 0; off >>= 1) x += __shfl_xor(x, off, 64);
  return x;
}

DINL u16 f2bf(float f) {
  unsigned u = __float_as_uint(f);
  unsigned r = u + 0x7fffu + ((u >> 16) & 1u);
  return (u16)(r >> 16);
}
DINL float bf2f(u16 h) { return __uint_as_float(((unsigned)h) << 16); }

// ---------- CSR build ----------
__global__ void k_deg(const int* __restrict__ dst, int* __restrict__ deg) {
  int e = blockIdx.x * 256 + threadIdx.x;
  if (e < Ee) atomicAdd(&deg[dst[e]], 1);
}

// block 0: serial scan of deg -> offs ; block 1: graph offsets from sorted batch
__global__ __launch_bounds__(1024) void k_pre(const int* __restrict__ deg,
                                              int* __restrict__ offs,
                                              const int* __restrict__ batch,
                                              int* __restrict__ goff) {
  int tid = threadIdx.x;
  if (blockIdx.x == 0) {
    __shared__ int part[1024];
    const int chunk = (Nn + 1023) >> 10;
    int start = tid * chunk;
    int s = 0;
    for (int k = 0; k < chunk; k++) { int i = start + k; if (i < Nn) s += deg[i]; }
    part[tid] = s;
    __syncthreads();
    for (int off = 1; off < 1024; off <<= 1) {
      int v = (tid >= off) ? part[tid - off] : 0;
      __syncthreads();
      part[tid] += v;
      __syncthreads();
    }
    int run = (tid == 0) ? 0 : part[tid - 1];
    for (int k = 0; k < chunk; k++) {
      int i = start + k;
      if (i < Nn) { offs[i] = run; run += deg[i]; }
    }
    if (start < Nn && start + chunk >= Nn) offs[Nn] = run;
  } else {
    for (int i = tid; i < Nn; i += 1024) {
      int bi = batch[i];
      int bp = (i == 0) ? -1 : batch[i - 1];
      for (int g = bp + 1; g <= bi; ++g) goff[g] = i;
      if (i == Nn - 1)
        for (int g = bi + 1; g <= Gg; ++g) goff[g] = Nn;
    }
  }
}

__global__ void k_fill(const int* __restrict__ src, const int* __restrict__ dst,
                       const int* __restrict__ offs, int* __restrict__ cursor,
                       int* __restrict__ csr) {
  int e = blockIdx.x * 256 + threadIdx.x;
  if (e < Ee) {
    int d = dst[e];
    int pos = atomicAdd(&cursor[d], 1);
    csr[offs[d] + pos] = src[e];
  }
}

// ---------- fused: weight split/transpose (W1|W2|Wm1) + proto_contrib/norms ----
__global__ void k_prep(const float* __restrict__ W1, const float* __restrict__ W2,
                       const float* __restrict__ Wm1, u16* __restrict__ W1th,
                       u16* __restrict__ W1tl, u16* __restrict__ W2th,
                       u16* __restrict__ W2tl, u16* __restrict__ Wm1th,
                       u16* __restrict__ Wm1tl, const float* __restrict__ proto,
                       const float* __restrict__ bm1, float* __restrict__ pcb,
                       float* __restrict__ pnorm) {
  int blk = blockIdx.x;
  if (blk >= 640) {  // blocks 640..655: proto_contrib + norms (one block/proto)
    int p = blk - 640, t = threadIdx.x;
    float s = bm1[t];
    for (int k = 0; k < Dd; k++)
      s += proto[p * Dd + k] * Wm1[(size_t)(Dd + k) * Dd + t];
    pcb[p * Dd + t] = s;
    if (t < 64) {
      float4 v = ((const float4*)(proto + (size_t)p * Dd))[t];
      float nsq = waveSum(v.x * v.x + v.y * v.y + v.z * v.z + v.w * v.w);
      if (t == 0) {
        float n = sqrtf(nsq);
        pnorm[p] = (n == 0.f) ? EPSf : n;
      }
    }
    return;
  }
  int idx = blk * 256 + threadIdx.x;
  const float* W;
  u16 *th, *tl;
  int K;
  if (idx < 128 * 256) {
    W = W1; th = W1th; tl = W1tl; K = 128;
  } else if (idx < 128 * 256 + 256 * 256) {
    idx -= 128 * 256;
    W = W2; th = W2th; tl = W2tl; K = 256;
  } else {
    idx -= 128 * 256 + 256 * 256;
    if (idx >= 256 * 256) return;
    W = Wm1; th = Wm1th; tl = Wm1tl; K = 256;
  }
  int k = idx >> 8, n = idx & 255;
  float v = W[idx];
  u16 h = f2bf(v);
  th[(size_t)n * K + k] = h;
  tl[(size_t)n * K + k] = f2bf(v - bf2f(h));
}

// ---------- 128B row-slice loader ----------
template <int DIM, int EPL, bool INBF>
DINL void slice(float r[EPL], const void* __restrict__ hv, int row, int ce) {
  if constexpr (INBF) {
    const u16* p = (const u16*)hv + (size_t)row * DIM + ce;
    ushort4 u = *(const ushort4*)p;
    r[0] = bf2f(u.x); r[1] = bf2f(u.y); r[2] = bf2f(u.z); r[3] = bf2f(u.w);
  } else {
    const float* p = (const float*)hv + (size_t)row * DIM + ce;
    float2 u = *(const float2*)p;
    r[0] = u.x; r[1] = u.y;
  }
}

// ---------- chunked edge aggregation (R6-proven form; at replication roofline) --
template <int DIM, int MODE, bool INBF, bool OSPL>
__global__ __launch_bounds__(256) void k_aggc(
    const void* __restrict__ hv, const float* __restrict__ nb,
    const int* __restrict__ offs, const int* __restrict__ csr,
    u16* __restrict__ oh, u16* __restrict__ ol) {
  constexpr int EPL = INBF ? 4 : 2;
  constexpr int COLS = EPL * 16;
  constexpr int CHUNKS = DIM / COLS;
  int c = (int)(blockIdx.x % CHUNKS);
  int grp = (int)(blockIdx.x / CHUNKS);
  int wv = threadIdx.x >> 6, lane = threadIdx.x & 63;
  int sub = lane >> 4, l = lane & 15;
  int node = grp * 16 + wv * 4 + sub;
  if (node >= Nn) return;
  int ce = c * COLS + l * EPL;
  float self[EPL], ts[EPL];
  slice<DIM, EPL, INBF>(self, hv, node, ce);
#pragma unroll
  for (int j = 0; j < EPL; j++) ts[j] = 0.f;
  int beg = offs[node], end = offs[node + 1];
  int k = beg;
  for (; k + 4 <= end; k += 4) {
    int s0 = csr[k], s1 = csr[k + 1], s2 = csr[k + 2], s3 = csr[k + 3];
    float r0[EPL], r1[EPL], r2[EPL], r3[EPL];
    slice<DIM, EPL, INBF>(r0, hv, s0, ce);
    slice<DIM, EPL, INBF>(r1, hv, s1, ce);
    slice<DIM, EPL, INBF>(r2, hv, s2, ce);
    slice<DIM, EPL, INBF>(r3, hv, s3, ce);
    if (MODE == 0) {
#pragma unroll
      for (int j = 0; j < EPL; j++) ts[j] += (r0[j] + r1[j]) + (r2[j] + r3[j]);
    } else {
      float w0 = nb[s0], w1 = nb[s1], w2 = nb[s2], w3 = nb[s3];
      if (MODE == 1) { w0 *= w0; w1 *= w1; w2 *= w2; w3 *= w3; }
#pragma unroll
      for (int j = 0; j < EPL; j++)
        ts[j] += (w0 * r0[j] + w1 * r1[j]) + (w2 * r2[j] + w3 * r3[j]);
    }
  }
  for (; k < end; k++) {
    int s = csr[k];
    float r[EPL];
    slice<DIM, EPL, INBF>(r, hv, s, ce);
    if (MODE == 0) {
#pragma unroll
      for (int j = 0; j < EPL; j++) ts[j] += r[j];
    } else {
      float wq = nb[s];
      if (MODE == 1) wq *= wq;
#pragma unroll
      for (int j = 0; j < EPL; j++) ts[j] += wq * r[j];
    }
  }
  float val[EPL];
  if (MODE == 0) {
#pragma unroll
    for (int j = 0; j < EPL; j++) val[j] = self[j] + ts[j];
  } else if (MODE == 1) {
    float wi = nb[node];
#pragma unroll
    for (int j = 0; j < EPL; j++) val[j] = wi * (self[j] + ts[j]);
  } else {
    float wi = nb[node];
#pragma unroll
    for (int j = 0; j < EPL; j++) val[j] = self[j] + wi * ts[j];
  }
  u16 hs[EPL], ls[EPL];
#pragma unroll
  for (int j = 0; j < EPL; j++) {
    hs[j] = f2bf(val[j]);
    if (OSPL) ls[j] = f2bf(val[j] - bf2f(hs[j]));
  }
  u16* po = oh + (size_t)node * DIM + ce;
  if constexpr (EPL == 2) {
    unsigned v = (unsigned)hs[0] | ((unsigned)hs[1] << 16);
    __builtin_nontemporal_store(v, (unsigned*)po);
  } else {
    u2v v;
    v.x = (unsigned)hs[0] | ((unsigned)hs[1] << 16);
    v.y = (unsigned)hs[2] | ((unsigned)hs[3] << 16);
    __builtin_nontemporal_store(v, (u2v*)po);
  }
  if constexpr (OSPL) {
    u16* pl = ol + (size_t)node * DIM + ce;
    if constexpr (EPL == 2) {
      unsigned v = (unsigned)ls[0] | ((unsigned)ls[1] << 16);
      __builtin_nontemporal_store(v, (unsigned*)pl);
    } else {
      u2v v;
      v.x = (unsigned)ls[0] | ((unsigned)ls[1] << 16);
      v.y = (unsigned)ls[2] | ((unsigned)ls[3] << 16);
      __builtin_nontemporal_store(v, (u2v*)pl);
    }
  }
}

// ---------- MFMA GEMM, 128x64 tile, XCD-swizzled 1D grid ----------
// SPLIT: 3-MFMA split-bf16 (~f32 precision). AF32: A staged from f32 source,
// hi/lo split in-register (masker path; avoids materializing neh/nel).
// EPI: 0 = relu+bias -> f32 store; 1 = relu+bias -> bf16 store;
//      2 = masker (pc/Wm2 dot -> per-row prob atomics).
// NOTE (R11 lesson): never fuse pooling via atomicAdd into a 256KB hot region.
template <int K, bool SPLIT, bool AF32, int EPI>
__global__ __launch_bounds__(256) void k_mm(
    const void* __restrict__ Av, const u16* __restrict__ Al,
    const u16* __restrict__ Bh, const u16* __restrict__ Bl,
    const float* __restrict__ bias,
    float* __restrict__ outF, u16* __restrict__ outH,
    const float* __restrict__ pc, const int* __restrict__ batch,
    const int* __restrict__ assign, const float* __restrict__ Wm2,
    float* __restrict__ prob) {
  // XCD swizzle: b = g*32 + c*8 + r -> panel = g*8+r, col = c
  int b = (int)blockIdx.x;
  int g = b >> 5, lane5 = b & 31;
  int panel = g * 8 + (lane5 & 7);
  int col = lane5 >> 3;
  if (panel >= 157) return;
  int rowBase = panel * 128, colBase = col * 64;

  constexpr int SK = 40;
  __shared__ u16 AsH[128 * SK];
  __shared__ u16 AsL[SPLIT ? 128 * SK : 16];
  __shared__ u16 BsH[64 * SK];
  __shared__ u16 BsL[SPLIT ? 64 * SK : 16];
  __shared__ int ap_s[128];
  int t = threadIdx.x;
  if (EPI == 2 && t < 128) {
    int r = rowBase + t;
    ap_s[t] = (r < Nn) ? assign[batch[r]] : 0;
  }
  int lane = t & 63, wv = t >> 6;
  int quad = lane >> 4, l16 = lane & 15;
  int wm = wv * 32;
  floatx4 acc[2][4];
#pragma unroll
  for (int mt = 0; mt < 2; mt++)
#pragma unroll
    for (int nt = 0; nt < 4; nt++) acc[mt][nt] = (floatx4){0.f, 0.f, 0.f, 0.f};

  int ar = t >> 1;            // 0..127: A row in tile (16 elements per thread)
  int ak = (t & 1) * 16;
  int bn = t >> 2;            // 0..63: B col in tile (8 u16 per thread)
  int bk = (t & 3) * 8;
  const u16* bgH = Bh + (size_t)(colBase + bn) * K + bk;
  const u16* bgL = Bl + (size_t)(colBase + bn) * K + bk;

  const u16* agH;
  const u16* agL;
  const float* agF;
  if constexpr (AF32) {
    agF = (const float*)Av + (size_t)(rowBase + ar) * K + ak;
  } else {
    agH = (const u16*)Av + (size_t)(rowBase + ar) * K + ak;
    agL = Al + (size_t)(rowBase + ar) * K + ak;
  }
  bool aok = AF32 ? (rowBase + ar < Nn) : true;

  // prologue: tile 0 into regs
  u4v cA0, cA1, cA0l, cA1l, cB0, cB0l;
  float4 fA[4];
  if constexpr (AF32) {
#pragma unroll
    for (int q = 0; q < 4; q++)
      fA[q] = aok ? ((const float4*)agF)[q] : make_float4(0.f, 0.f, 0.f, 0.f);
  } else {
    cA0 = *(const u4v*)(agH);
    cA1 = *(const u4v*)(agH + 8);
    if constexpr (SPLIT) {
      cA0l = *(const u4v*)(agL);
      cA1l = *(const u4v*)(agL + 8);
    }
  }
  cB0 = *(const u4v*)(bgH);
  if constexpr (SPLIT) cB0l = *(const u4v*)(bgL);

  for (int k0 = 0; k0 < K; k0 += 32) {
    __syncthreads();
    if constexpr (AF32) {
      u16 hh[16], ll[16];
#pragma unroll
      for (int q = 0; q < 4; q++) {
        const float vv[4] = {fA[q].x, fA[q].y, fA[q].z, fA[q].w};
#pragma unroll
        for (int j = 0; j < 4; j++) {
          u16 h = f2bf(vv[j]);
          hh[q * 4 + j] = h;
          ll[q * 4 + j] = f2bf(vv[j] - bf2f(h));
        }
      }
      *(u4v*)&AsH[ar * SK + ak] = *(const u4v*)&hh[0];
      *(u4v*)&AsH[ar * SK + ak + 8] = *(const u4v*)&hh[8];
      *(u4v*)&AsL[ar * SK + ak] = *(const u4v*)&ll[0];
      *(u4v*)&AsL[ar * SK + ak + 8] = *(const u4v*)&ll[8];
    } else {
      *(u4v*)&AsH[ar * SK + ak] = cA0;
      *(u4v*)&AsH[ar * SK + ak + 8] = cA1;
      if constexpr (SPLIT) {
        *(u4v*)&AsL[ar * SK + ak] = cA0l;
        *(u4v*)&AsL[ar * SK + ak + 8] = cA1l;
      }
    }
    *(u4v*)&BsH[bn * SK + bk] = cB0;
    if constexpr (SPLIT) *(u4v*)&BsL[bn * SK + bk] = cB0l;
    __syncthreads();
    if (k0 + 32 < K) {  // prefetch next K-tile; latency overlaps MFMAs below
      if constexpr (AF32) {
#pragma unroll
        for (int q = 0; q < 4; q++)
          fA[q] = aok ? ((const float4*)(agF + k0 + 32))[q]
                      : make_float4(0.f, 0.f, 0.f, 0.f);
      } else {
        cA0 = *(const u4v*)(agH + k0 + 32);
        cA1 = *(const u4v*)(agH + k0 + 40);
        if constexpr (SPLIT) {
          cA0l = *(const u4v*)(agL + k0 + 32);
          cA1l = *(const u4v*)(agL + k0 + 40);
        }
      }
      cB0 = *(const u4v*)(bgH + k0 + 32);
      if constexpr (SPLIT) cB0l = *(const u4v*)(bgL + k0 + 32);
    }
    short8 aH[2], aL[2], bH[4], bL[4];
#pragma unroll
    for (int mt = 0; mt < 2; mt++) {
      int aoff = (wm + mt * 16 + l16) * SK + quad * 8;
      aH[mt] = *(const short8*)&AsH[aoff];
      if (SPLIT) aL[mt] = *(const short8*)&AsL[aoff];
    }
#pragma unroll
    for (int nt = 0; nt < 4; nt++) {
      int boff = (nt * 16 + l16) * SK + quad * 8;
      bH[nt] = *(const short8*)&BsH[boff];
      if (SPLIT) bL[nt] = *(const short8*)&BsL[boff];
    }
#pragma unroll
    for (int mt = 0; mt < 2; mt++)
#pragma unroll
      for (int nt = 0; nt < 4; nt++) {
        acc[mt][nt] = __builtin_amdgcn_mfma_f32_16x16x32_bf16(aH[mt], bH[nt], acc[mt][nt], 0, 0, 0);
        if constexpr (SPLIT) {
          acc[mt][nt] = __builtin_amdgcn_mfma_f32_16x16x32_bf16(aH[mt], bL[nt], acc[mt][nt], 0, 0, 0);
          acc[mt][nt] = __builtin_amdgcn_mfma_f32_16x16x32_bf16(aL[mt], bH[nt], acc[mt][nt], 0, 0, 0);
        }
      }
  }

  if constexpr (EPI == 0 || EPI == 1) {
#pragma unroll
    for (int mt = 0; mt < 2; mt++)
#pragma unroll
      for (int nt = 0; nt < 4; nt++) {
        int cc = colBase + nt * 16 + l16;
        float bv = bias[cc];
#pragma unroll
        for (int r = 0; r < 4; r++) {
          int row = rowBase + wm + mt * 16 + quad * 4 + r;
          if (row < Nn) {
            float v = fmaxf(acc[mt][nt][r] + bv, 0.f);
            if constexpr (EPI == 0) {
              outF[(size_t)row * 256 + cc] = v;
            } else {
              outH[(size_t)row * 256 + cc] = f2bf(v);
            }
          }
        }
      }
  } else {  // EPI == 2: masker
#pragma unroll
    for (int mt = 0; mt < 2; mt++) {
      float part[4] = {0.f, 0.f, 0.f, 0.f};
#pragma unroll
      for (int nt = 0; nt < 4; nt++) {
        int cc = colBase + nt * 16 + l16;
        float wmv = Wm2[cc];
#pragma unroll
        for (int r = 0; r < 4; r++) {
          int ap = ap_s[wm + mt * 16 + quad * 4 + r];
          float tv = fmaxf(acc[mt][nt][r] + pc[ap * 256 + cc], 0.f);
          part[r] += tv * wmv;
        }
      }
#pragma unroll
      for (int r = 0; r < 4; r++) {
#pragma unroll
        for (int off = 1; off < 16; off <<= 1) part[r] += __shfl_xor(part[r], off, 64);
        if (l16 == 0) {
          int row = rowBase + wm + mt * 16 + quad * 4 + r;
          if (row < Nn) atomicAdd(&prob[row], part[r]);
        }
      }
    }
  }
}

// ---------- pool (sequential order! argmax-sensitive) + prototype argmax ------
__global__ __launch_bounds__(256) void k_poolassign(
    const float* __restrict__ h, const int* __restrict__ goff,
    const float* __restrict__ proto, const float* __restrict__ pnorm,
    int* __restrict__ assign) {
  __shared__ float row[Dd];
  int g = blockIdx.x, c = threadIdx.x;
  int beg = goff[g], end = goff[g + 1];
  float s = 0.f;
  for (int n = beg; n < end; ++n)
    s += __builtin_nontemporal_load(&h[(size_t)n * Dd + c]);
  row[c] = s;
  __syncthreads();
  if (c < 64) {
    float4 v = ((const float4*)row)[c];
    float na = sqrtf(waveSum(v.x * v.x + v.y * v.y + v.z * v.z + v.w * v.w));
    if (na == 0.f) na = EPSf;
    float best = -1e30f;
    int bi = 0;
#pragma unroll
    for (int p = 0; p < Pp; p++) {
      float4 w = *(const float4*)(proto + (size_t)p * Dd + c * 4);
      float d = waveSum(v.x * w.x + v.y * w.y + v.z * w.z + v.w * w.w);
      float sim = d / (na * pnorm[p]);
      if (sim > best) { best = sim; bi = p; }
    }
    if (c == 0) assign[g] = bi;
  }
}

// ---------- pool + similarity + NCE (pass 2), fused ----------
__global__ __launch_bounds__(256) void k_poolsim(
    const float* __restrict__ h, const int* __restrict__ goff,
    const float* __restrict__ proto, const float* __restrict__ pnorm,
    float* __restrict__ o_sg, float* __restrict__ sgemb,
    float* __restrict__ osim, float* __restrict__ snorm,
    float* __restrict__ nceAcc) {
  __shared__ float row[Dd];
  int g = blockIdx.x, c = threadIdx.x;
  int beg = goff[g], end = goff[g + 1];
  float s = 0.f;
  for (int n = beg; n < end; ++n)
    s += __builtin_nontemporal_load(&h[(size_t)n * Dd + c]);
  row[c] = s;
  o_sg[(size_t)g * Dd + c] = s;
  sgemb[(size_t)g * Dd + c] = s;
  __syncthreads();
  if (c < 64) {
    float4 v = ((const float4*)row)[c];
    float na = sqrtf(waveSum(v.x * v.x + v.y * v.y + v.z * v.z + v.w * v.w));
    if (na == 0.f) na = EPSf;
    float sims[Pp];
#pragma unroll
    for (int p = 0; p < Pp; p++) {
      float4 w = *(const float4*)(proto + (size_t)p * Dd + c * 4);
      float d = waveSum(v.x * w.x + v.y * w.y + v.z * w.z + v.w * w.w);
      float sim = d / (na * pnorm[p]);
      sims[p] = sim;
      if (c == p) osim[g * Pp + p] = sim;
    }
    float best = sims[0];
    int bi = 0;
#pragma unroll
    for (int p = 1; p < Pp; p++) {
      if (sims[p] > best) { best = sims[p]; bi = p; }
    }
    float pos = 0.f, neg = 0.f;
#pragma unroll
    for (int p = 0; p < Pp; p++) {
      float e = expf(sims[p] / TEMPf);
      if (p == bi) pos = e; else neg += e;
    }
    if (c == 0) {
      atomicAdd(nceAcc, -logf(pos / neg));
      snorm[g] = na;
    }
  }
}

// ---------- node_bern+KL | edge_bern+KL | x->bf16, fused by block range ----------
__global__ void k_berneb(const float* __restrict__ prob, const float* __restrict__ bm2,
                         const int* __restrict__ src, const int* __restrict__ dst,
                         const float* __restrict__ x, u16* __restrict__ xbf,
                         float* __restrict__ ob, float* __restrict__ oe,
                         float* __restrict__ accs) {
  const int nB = (Nn + 255) / 256, eB = (Ee + 255) / 256;
  int b = blockIdx.x;
  if (b < nB) {
    int i = b * 256 + threadIdx.x;
    float val = 0.f;
    if (i < Nn) {
      float z = prob[i] + bm2[0];
      float p = 1.f / (1.f + expf(-z));
      ob[i] = p;
      const float invA = 1.f / Rf, invB = 1.f / (1.f - Rf + EPSf);
      val = p * logf(p * invA + EPSf) + (1.f - p) * logf((1.f - p) * invB + EPSf);
    }
    val = waveSum(val);
    __shared__ float wsum[4];
    int lane = threadIdx.x & 63, wvv = threadIdx.x >> 6;
    if (lane == 0) wsum[wvv] = val;
    __syncthreads();
    if (threadIdx.x == 0) atomicAdd(accs, wsum[0] + wsum[1] + wsum[2] + wsum[3]);
  } else if (b < nB + eB) {
    int e = (b - nB) * 256 + threadIdx.x;
    float val = 0.f;
    if (e < Ee) {
      float zs = prob[src[e]] + bm2[0];
      float zd = prob[dst[e]] + bm2[0];
      float ps = 1.f / (1.f + expf(-zs));
      float pd = 1.f / (1.f + expf(-zd));
      float v = ps * pd;
      __builtin_nontemporal_store(v, &oe[e]);
      const float invA = 1.f / (Rf * Rf), invB = 1.f / (1.f - Rf * Rf + EPSf);
      val = v * logf(v * invA + EPSf) + (1.f - v) * logf((1.f - v) * invB + EPSf);
    }
    val = waveSum(val);
    __shared__ float wsum2[4];
    int lane = threadIdx.x & 63, wvv = threadIdx.x >> 6;
    if (lane == 0) wsum2[wvv] = val;
    __syncthreads();
    if (threadIdx.x == 0) atomicAdd(accs + 1, wsum2[0] + wsum2[1] + wsum2[2] + wsum2[3]);
  } else {
    int i = (b - nB - eB) * 256 + threadIdx.x;
    if (i < Nn * 128 / 4) {
      float4 v = ((const float4*)x)[i];
      u2v o;
      o.x = (unsigned)f2bf(v.x) | ((unsigned)f2bf(v.y) << 16);
      o.y = (unsigned)f2bf(v.z) | ((unsigned)f2bf(v.w) << 16);
      __builtin_nontemporal_store(o, (u2v*)&xbf[(size_t)i * 4]);
    }
  }
}

// ---------- data_sim (+ final scalar outputs folded into block 0) ----------
__global__ void k_datasim(const float* __restrict__ S, const float* __restrict__ snorm,
                          float* __restrict__ out, const float* __restrict__ accs,
                          float* __restrict__ o_kl, float* __restrict__ o_nce) {
  int i = blockIdx.x, j = threadIdx.x;
  if (i == 0 && j == 0) {
    o_kl[0] = accs[0] / (float)Nn + accs[1] / (float)Ee;
    o_nce[0] = accs[2] / (float)Gg;
  }
  __shared__ float si[Dd];
  si[j] = S[(size_t)i * Dd + j];
  __syncthreads();
  const float4* rj = (const float4*)(S + (size_t)j * Dd);
  const float4* sif = (const float4*)si;
  float d = 0.f;
#pragma unroll 4
  for (int k = 0; k < Dd / 4; k++) {
    float4 a = sif[k];
    float4 b = rj[k];
    d += a.x * b.x + a.y * b.y + a.z * b.z + a.w * b.w;
  }
  out[(size_t)i * Gg + j] = d / (snorm[i] * snorm[j]);
}

}  // namespace

extern "C" void kernel_launch(void* const* d_in, const int* in_sizes, int n_in,
                              void* d_out, int out_size, void* d_ws, size_t ws_size,
                              hipStream_t stream) {
  const float* x = (const float*)d_in[0];
  const int* ei = (const int*)d_in[1];
  const int* batch = (const int*)d_in[2];
  const float* W1 = (const float*)d_in[3];
  const float* b1 = (const float*)d_in[4];
  const float* W2 = (const float*)d_in[5];
  const float* b2 = (const float*)d_in[6];
  const float* Wm1 = (const float*)d_in[7];
  const float* bm1 = (const float*)d_in[8];
  const float* Wm2 = (const float*)d_in[9];
  const float* bm2 = (const float*)d_in[10];
  const float* proto = (const float*)d_in[11];
  const int* src = ei;
  const int* dst = ei + Ee;

  float* out = (float*)d_out;
  float* o_kl = out;
  float* o_nce = out + 1;
  float* o_sim = out + 2;
  float* o_nb = o_sim + Gg * Pp;
  float* o_eb = o_nb + Nn;
  float* o_ds = o_eb + Ee;
  float* o_sg = o_ds + Gg * Gg;
  float* o_ne = o_sg + Gg * Dd;

  char* w = (char*)d_ws;
  auto take = [&](size_t bytes) -> char* {
    char* p = w;
    w += (bytes + 255) & ~(size_t)255;
    return p;
  };
  const size_t halfR = (size_t)Npad * 256 * 2;
  float* bufB = (float*)take((size_t)Npad * 256 * 4);
  char* R2 = take(2 * halfR);
  u16* A1h = (u16*)R2;
  u16* A1l = (u16*)(R2 + (size_t)Npad * 128 * 2);
  u16* A2h = (u16*)R2;
  u16* A2l = (u16*)(R2 + halfR);
  u16* h1b = (u16*)R2;            // pass2: over A2h (dead)
  u16* a2bh = (u16*)(R2 + halfR); // pass2: over A2l (dead)
  u16* a1bh = (u16*)take((size_t)Npad * 128 * 2);
  u16* xbf = (u16*)take((size_t)Nn * 128 * 2);  // dedicated (no aliasing)

  int* csr = (int*)take((size_t)Ee * 4);
  // zero-init region (contiguous -> ONE memset): deg, cursor, prob, accs
  int* deg = (int*)take((size_t)Nn * 4);       // 80128
  int* cursor = (int*)take((size_t)Nn * 4);    // 80128
  float* prob = (float*)take(Nn * 4);          // 80128
  float* accs = (float*)take(16);              // 256
  float* sgemb = (float*)take((size_t)Gg * Dd * 4);
  int* offs = (int*)take((size_t)(Nn + 1) * 4);
  int* goff = (int*)take((size_t)(Gg + 1) * 4);
  float* pcb = (float*)take((size_t)Pp * Dd * 4);
  float* pnorm = (float*)take(Pp * 4);
  int* assign = (int*)take(Gg * 4);
  float* snorm = (float*)take(Gg * 4);
  u16* W1th = (u16*)take((size_t)256 * 128 * 2);
  u16* W1tl = (u16*)take((size_t)256 * 128 * 2);
  u16* W2th = (u16*)take((size_t)256 * 256 * 2);
  u16* W2tl = (u16*)take((size_t)256 * 256 * 2);
  u16* Wm1th = (u16*)take((size_t)256 * 256 * 2);
  u16* Wm1tl = (u16*)take((size_t)256 * 256 * 2);

  hipMemsetAsync(deg, 0, 3 * 80128 + 256, stream);

  const int eB = (Ee + 255) / 256;
  const int nB = (Nn + 255) / 256;
  const int gmm = 640;  // 20 super-groups x 32, XCD-swizzled

  k_deg<<<eB, 256, 0, stream>>>(dst, deg);
  k_pre<<<2, 1024, 0, stream>>>(deg, offs, batch, goff);
  k_fill<<<eB, 256, 0, stream>>>(src, dst, offs, cursor, csr);
  k_prep<<<656, 256, 0, stream>>>(W1, W2, Wm1, W1th, W1tl, W2th, W2tl, Wm1th, Wm1tl,
                                  proto, bm1, pcb, pnorm);

  // ---- pass 1 (split-bf16 GEMMs, f32 chunked gathers) ----
  k_aggc<128, 0, false, true><<<1250 * 4, 256, 0, stream>>>(x, nullptr, offs, csr, A1h, A1l);
  k_mm<128, true, false, 0><<<gmm, 256, 0, stream>>>(A1h, A1l, W1th, W1tl, b1, bufB,
                                                     nullptr, nullptr, nullptr, nullptr,
                                                     nullptr, nullptr);
  k_aggc<256, 0, false, true><<<1250 * 8, 256, 0, stream>>>(bufB, nullptr, offs, csr, A2h, A2l);
  k_mm<256, true, false, 0><<<gmm, 256, 0, stream>>>(A2h, A2l, W2th, W2tl, b2, o_ne,
                                                     nullptr, nullptr, nullptr, nullptr,
                                                     nullptr, nullptr);
  k_poolassign<<<Gg, 256, 0, stream>>>(o_ne, goff, proto, pnorm, assign);
  // masker: A staged from o_ne (f32), split in-register; 3-MFMA precision kept
  k_mm<256, true, true, 2><<<gmm, 256, 0, stream>>>(o_ne, nullptr, Wm1th, Wm1tl,
                                                    nullptr, nullptr, nullptr, pcb,
                                                    batch, assign, Wm2, prob);
  // bern + eb + x->bf16 in one launch
  k_berneb<<<nB + eB + (Nn * 128 / 4 + 255) / 256, 256, 0, stream>>>(
      prob, bm2, src, dst, x, xbf, o_nb, o_eb, accs);

  // ---- pass 2 (plain bf16 GEMMs, bf16 chunked gathers) ----
  k_aggc<128, 1, true, false><<<1250 * 2, 256, 0, stream>>>(xbf, o_nb, offs, csr, a1bh, nullptr);
  k_mm<128, false, false, 1><<<gmm, 256, 0, stream>>>(a1bh, nullptr, W1th, nullptr, b1,
                                                      nullptr, h1b, nullptr, nullptr,
                                                      nullptr, nullptr, nullptr);
  k_aggc<256, 2, true, false><<<1250 * 4, 256, 0, stream>>>(h1b, o_nb, offs, csr, a2bh, nullptr);
  k_mm<256, false, false, 0><<<gmm, 256, 0, stream>>>(a2bh, nullptr, W2th, nullptr, b2,
                                                      bufB, nullptr, nullptr, nullptr,
                                                      nullptr, nullptr, nullptr);
  k_poolsim<<<Gg, 256, 0, stream>>>(bufB, goff, proto, pnorm, o_sg, sgemb, o_sim, snorm,
                                    accs + 2);
  k_datasim<<<Gg, 256, 0, stream>>>(sgemb, snorm, o_ds, accs, o_kl, o_nce);
}